// Round 2
// baseline (421.481 us; speedup 1.0000x reference)
//
#include <hip/hip_runtime.h>
#include <hip/hip_bf16.h>

// SpatialContextNet on MI355X (gfx950). Round 5.
// GEMM: 256x256 tile, BK=32, 4-buffer LDS (3-tile-deep prefetch), ONE barrier
// + ONE counted vmcnt(8) per K-tile, persistent blocks (2 nb tiles, grid=256
// = 1 block/CU, single round). Theory: R3/R4 both pinned at ~25 B/cy/CU
// global_load_lds delivery (latency-exposed at 1 block/CU, 2-deep prefetch);
// depth-3 + minimal sync restores overlap (m97 precedent: 57 B/cy/CU).
// Aux: transpose float4 loads; corr chain CS=4 (halves part traffic).
//
// feature [8,1024,64,64] f32, conv_w [1024,1049] f32, conv_b [1024] f32.
// Out [8,1024,64,64] f32.

typedef __attribute__((ext_vector_type(8))) short short8x;
typedef __attribute__((ext_vector_type(4))) float floatx4;

#define B_   8
#define C_   1024
#define HW_  4096
#define KPAD 1088
#define CS_  4     // channel chunks for corr partials
#define CCH  256   // channels per chunk
#define NKT  34    // K tiles of 32 per GEMM pass (34*32 = 1088)

__device__ __forceinline__ unsigned short f2bf(float f) {
  unsigned int u = __float_as_uint(f);
  u += 0x7FFFu + ((u >> 16) & 1u);
  return (unsigned short)(u >> 16);
}

__device__ __forceinline__ void async16(const void* g, void* l) {
  __builtin_amdgcn_global_load_lds(
      (__attribute__((address_space(1))) void*)(void*)g,
      (__attribute__((address_space(3))) void*)l, 16, 0, 0);
}

__device__ __forceinline__ short8x rd16(const char* p) {
  return *(const short8x*)p;
}

// ---- K1: correlation partials, wave-per-row, no LDS ------------------------
// grid (8 ystrips, 4 cs, 8 b), block 512 (8 waves = 8 rows).
// part[(cs*25+j)*32768 + b*4096 + y*64 + x]  (f32)
__global__ __launch_bounds__(512) void scn_corr_part(
    const float* __restrict__ f, float* __restrict__ part) {
  const int tid = threadIdx.x;
  const int x = tid & 63;
  const int y = blockIdx.x * 8 + (tid >> 6);
  const int cs = blockIdx.y, b = blockIdx.z;

  const int xs0 = (x + 2 < 64) ? x + 2 : 63;
  const int xs1 = (x + 1 < 64) ? x + 1 : 63;
  const int xs3 = (x - 1 >= 0) ? x - 1 : 0;
  const int xs4 = (x - 2 >= 0) ? x - 2 : 0;

  const bool ym2 = (y >= 2), ym1 = (y >= 1), yp1 = (y <= 62), yp2 = (y <= 61);

  const float* rp0 = f + ((size_t)b * C_ + cs * CCH) * HW_ + y * 64;

  float h[25];
#pragma unroll
  for (int j = 0; j < 25; ++j) h[j] = 0.f;

#pragma unroll 4
  for (int c = 0; c < CCH; ++c) {
    const float* rp = rp0 + (size_t)c * HW_;
    const float ctr = rp[x];
    const float vm2 = ym2 ? rp[x - 128] : 0.f;
    const float vm1 = ym1 ? rp[x - 64] : 0.f;
    const float vp1 = yp1 ? rp[x + 64] : 0.f;
    const float vp2 = yp2 ? rp[x + 128] : 0.f;
    const float c0 = rp[xs0], c1 = rp[xs1], c3 = rp[xs3], c4 = rp[xs4];
    const float v[5] = {vm2, vm1, ctr, vp1, vp2};
    const float cc[5] = {c0, c1, ctr, c3, c4};
#pragma unroll
    for (int dxi = 0; dxi < 5; ++dxi)
#pragma unroll
      for (int dyi = 0; dyi < 5; ++dyi)
        h[dxi * 5 + dyi] = fmaf(v[dyi], cc[dxi], h[dxi * 5 + dyi]);
  }

  float* pb = part + (size_t)(cs * 25) * 32768 + b * HW_ + y * 64;
#pragma unroll
  for (int j = 0; j < 25; ++j) {
    const int dx = (j / 5) - 2;
    const int tgt = x - dx;
    const int wx = (tgt + 64) & 63;
    const float val = ((unsigned)tgt < 64u) ? h[j] : 0.f;
    pb[(size_t)j * 32768 + wx] = val;
  }
}

// ---- K2: transpose-cast feature [b][k][m] -> At [b][m][k] bf16 -------------
// grid (64 mtiles, 16 ktiles, 8 b), block 256; 64x64 tiles; float4 loads.
__global__ __launch_bounds__(256) void scn_transpose(
    const float* __restrict__ f, unsigned short* __restrict__ At) {
  __shared__ float lds[64][65];
  const int mt = blockIdx.x, kt = blockIdx.y, b = blockIdx.z;
  const int tid = threadIdx.x;
  const int m4 = (tid & 15) << 2, kr0 = tid >> 4;
  const float* src = f + ((size_t)b * C_ + kt * 64 + kr0) * HW_ + mt * 64 + m4;
#pragma unroll
  for (int i = 0; i < 4; ++i) {
    floatx4 v = *(const floatx4*)(src + (size_t)i * 16 * HW_);
    float* d = &lds[kr0 + i * 16][m4];
    d[0] = v[0]; d[1] = v[1]; d[2] = v[2]; d[3] = v[3];
  }
  __syncthreads();
  unsigned short* dst = At + ((size_t)b * HW_ + mt * 64) * KPAD + kt * 64;
  const int c = tid & 7, mr = tid >> 3;
#pragma unroll
  for (int half = 0; half < 2; ++half) {
    const int mm = mr + half * 32;
    short8x v;
#pragma unroll
    for (int j = 0; j < 8; ++j) v[j] = (short)f2bf(lds[c * 8 + j][mm]);
    *(short8x*)(dst + (size_t)mm * KPAD + c * 8) = v;
  }
}

// ---- K3: inv norm from j=12 partial slices ---------------------------------
__global__ __launch_bounds__(256) void scn_invn(const float* __restrict__ part,
                                                float* __restrict__ invn) {
  const int i = blockIdx.x * 256 + threadIdx.x;
  float s = 0.f;
#pragma unroll
  for (int cs = 0; cs < CS_; ++cs) s += part[(size_t)(cs * 25 + 12) * 32768 + i];
  invn[i] = 1.0f / fmaxf(sqrtf(s), 1e-12f);
}

// ---- K4: reduce partials over cs, apply norms, write At rows 1024..1087 ----
__global__ __launch_bounds__(256) void scn_corr_reduce(
    const float* __restrict__ part, const float* __restrict__ invn,
    unsigned short* __restrict__ At) {
  const int b = blockIdx.y;
  const int m = blockIdx.x * 256 + threadIdx.x;
  const int i = b * HW_ + m;
  const int y = m >> 6, x = m & 63;

  float acc[25];
#pragma unroll
  for (int j = 0; j < 25; ++j) acc[j] = 0.f;
#pragma unroll 1
  for (int cs = 0; cs < CS_; ++cs) {
    const float* pb = part + (size_t)(cs * 25) * 32768 + i;
#pragma unroll
    for (int j = 0; j < 25; ++j) acc[j] += pb[(size_t)j * 32768];
  }
  const float ic = invn[i];
  unsigned short r[64];
#pragma unroll
  for (int j = 0; j < 25; ++j) {
    const int dy = (j % 5) - 2, dx = (j / 5) - 2;
    const int ny = y + dy, nx = x + dx;
    float in2 = (ny >= 0 && ny < 64 && nx >= 0 && nx < 64)
                    ? invn[b * HW_ + (ny << 6) + nx] : 0.f;
    r[j] = f2bf(acc[j] * ic * in2);
  }
#pragma unroll
  for (int j = 25; j < 64; ++j) r[j] = 0;
  unsigned short* row = At + ((size_t)b * HW_ + m) * KPAD + 1024;
#pragma unroll
  for (int v = 0; v < 8; ++v) *(short8x*)(row + v * 8) = *(short8x*)(r + v * 8);
}

// ---- K5: cast+pad conv_w -> Wb [1024][1088] bf16 ---------------------------
__global__ __launch_bounds__(256) void scn_wcast(const float* __restrict__ w,
                                                 unsigned short* __restrict__ Wb) {
  const int i = blockIdx.x * 256 + threadIdx.x;
  const int o = i / KPAD, k = i - o * KPAD;
  Wb[i] = (k < 1049) ? f2bf(w[(size_t)o * 1049 + k]) : 0;
}

// ---- K6: bf16 MFMA GEMM 256x256/BK=32, 4-buffer pipeline, persistent -------
// grid (8 nb2, 4 ob, 8 b) = 256 blocks, block 512 (8 waves: wm=wid>>2, wn=wid&3).
// LDS: 4 buffers x 32 KB { A [128 rho][8 slots], B same at +16384 }.
// Slot sc of row rho holds content v = sc ^ (rho&7), v = h*4+c:
//   global row = h*128 + rho, col-slice c (8 elems). Linear global_load_lds
//   dest + inverse-swizzled source; swizzled ds_read (conflict-free, = R4).
// Per kt: [vmcnt(8); s_barrier; STAGE(t+3); 12 ds_read; lgkm(0); 32 MFMA].
// Persistent: 68 kt = 2 passes of 34 (nb = nb2*2 + pass), epilogue0 mid-loop.
__global__ __launch_bounds__(512, 2) void scn_gemm(
    const unsigned short* __restrict__ Wb, const unsigned short* __restrict__ At,
    const float* __restrict__ bias, float* __restrict__ out) {
  extern __shared__ char lds[];
  const int tid = threadIdx.x;
  const int l = tid & 63;
  const int wid = tid >> 6;
  const int wm = wid >> 2, wn = wid & 3;
  const int nb2 = blockIdx.x, ob = blockIdx.y, b = blockIdx.z;

  // staging sources for LDS slots s0=tid, s1=tid+512 (inverse swizzle)
  const int r0 = tid >> 3, v0 = (tid & 7) ^ (r0 & 7);
  const int r1 = (tid + 512) >> 3, v1 = (tid & 7) ^ (r1 & 7);
  const unsigned short* gA0 =
      Wb + (size_t)(ob * 256 + (v0 >> 2) * 128 + r0) * KPAD + (v0 & 3) * 8;
  const unsigned short* gA1 =
      Wb + (size_t)(ob * 256 + (v1 >> 2) * 128 + r1) * KPAD + (v1 & 3) * 8;
  const unsigned short* gB0 =
      At + ((size_t)b * HW_ + nb2 * 512 + (v0 >> 2) * 128 + r0) * KPAD + (v0 & 3) * 8;
  const unsigned short* gB1 =
      At + ((size_t)b * HW_ + nb2 * 512 + (v1 >> 2) * 128 + r1) * KPAD + (v1 & 3) * 8;

#define STAGE(tau_) do {                                                \
    int tau = (tau_); if (tau >= 2 * NKT) tau = 0;                      \
    const int pass_ = (tau >= NKT) ? 1 : 0;                             \
    const size_t ko = (size_t)(tau - NKT * pass_) * 32;                 \
    const size_t bo = (size_t)pass_ * 256 * KPAD + ko;                  \
    char* dst = lds + (size_t)(tau & 3) * 32768;                        \
    async16(gA0 + ko, dst + tid * 16);                                  \
    async16(gA1 + ko, dst + 8192 + tid * 16);                           \
    async16(gB0 + bo, dst + 16384 + tid * 16);                          \
    async16(gB1 + bo, dst + 24576 + tid * 16);                          \
  } while (0)

  // read-side swizzled lane offsets
  const int l15 = l & 15, l4g = l >> 4, l7 = l & 7;
  const int aoffc = l15 * 128 + (((wm * 4 + l4g) ^ l7) << 4);
  const int boffc = ((wn & 1) * 64 + l15) * 128 +
                    (((((wn >> 1) * 4) + l4g) ^ l7) << 4) + 16384;

  floatx4 acc[8][4];
#pragma unroll
  for (int i = 0; i < 8; ++i)
#pragma unroll
    for (int j = 0; j < 4; ++j) acc[i][j] = (floatx4){0.f, 0.f, 0.f, 0.f};

  float* const outb = out + (size_t)b * C_ * HW_;
  auto write_out = [&](int nbe) __attribute__((always_inline)) {
#pragma unroll
    for (int i = 0; i < 8; ++i) {
      const int o0 = ob * 256 + wm * 128 + i * 16 + l4g * 4;
      float bs[4];
#pragma unroll
      for (int r = 0; r < 4; ++r) bs[r] = bias[o0 + r];
#pragma unroll
      for (int j = 0; j < 4; ++j) {
        const int m = nbe * 256 + wn * 64 + j * 16 + l15;
#pragma unroll
        for (int r = 0; r < 4; ++r) {
          float v = acc[i][j][r] + bs[r];
          outb[(size_t)(o0 + r) * HW_ + m] = v > 0.f ? v : 0.f;
        }
      }
    }
  };

  STAGE(0); STAGE(1); STAGE(2);

  for (int t = 0; t < 2 * NKT; ++t) {
    const char* base = lds + (size_t)(t & 3) * 32768;
    asm volatile("s_waitcnt vmcnt(8)" ::: "memory");  // tile t landed (all waves)
    __builtin_amdgcn_s_barrier();                     // ... published
    STAGE(t + 3);  // -> buf[(t-1)&3]: all reads of tile t-1 retired pre-barrier
    short8x a[8], bfr[4];
#pragma unroll
    for (int i = 0; i < 8; ++i) a[i] = rd16(base + i * 2048 + aoffc);
#pragma unroll
    for (int j = 0; j < 4; ++j) bfr[j] = rd16(base + j * 2048 + boffc);
    asm volatile("s_waitcnt lgkmcnt(0)" ::: "memory");
    __builtin_amdgcn_sched_barrier(0);
    __builtin_amdgcn_s_setprio(1);
#pragma unroll
    for (int i = 0; i < 8; ++i)
#pragma unroll
      for (int j = 0; j < 4; ++j)
        acc[i][j] = __builtin_amdgcn_mfma_f32_16x16x32_bf16(a[i], bfr[j],
                                                            acc[i][j], 0, 0, 0);
    __builtin_amdgcn_s_setprio(0);
    if (t == NKT - 1) {  // pass-0 epilogue; stores retire on L2-ack
      write_out(nb2 * 2);
#pragma unroll
      for (int i = 0; i < 8; ++i)
#pragma unroll
        for (int j = 0; j < 4; ++j) acc[i][j] = (floatx4){0.f, 0.f, 0.f, 0.f};
    }
  }
  asm volatile("s_waitcnt vmcnt(0)" ::: "memory");
  write_out(nb2 * 2 + 1);
#undef STAGE
}

// ---- launch ----------------------------------------------------------------
extern "C" void kernel_launch(void* const* d_in, const int* in_sizes, int n_in,
                              void* d_out, int out_size, void* d_ws, size_t ws_size,
                              hipStream_t stream) {
  const float* feature = (const float*)d_in[0];
  const float* conv_w  = (const float*)d_in[1];
  const float* conv_b  = (const float*)d_in[2];
  float* out = (float*)d_out;

  // workspace layout (bytes), total 84,541,440:
  //   At   [32768][1088] bf16 : 0          .. 71,303,168
  //   part [4*25][32768] f32  : 71,303,168 .. 84,410,368
  //   Wb   [1024][1088] bf16  : aliases part (part dead after corr_reduce)
  //   invn [32768] f32        : 84,410,368 .. 84,541,440
  char* ws = (char*)d_ws;
  unsigned short* At = (unsigned short*)(ws);
  float* part        = (float*)(ws + 71303168);
  unsigned short* Wb = (unsigned short*)(ws + 71303168);  // aliases part
  float* invn        = (float*)(ws + 84410368);

  static int gemm_attr_set = 0;
  if (!gemm_attr_set) {
    hipFuncSetAttribute((const void*)scn_gemm,
                        hipFuncAttributeMaxDynamicSharedMemorySize, 131072);
    gemm_attr_set = 1;
  }

  scn_corr_part<<<dim3(8, CS_, 8), 512, 0, stream>>>(feature, part);
  scn_transpose<<<dim3(64, 16, 8), 256, 0, stream>>>(feature, At);
  scn_invn<<<dim3(128), 256, 0, stream>>>(part, invn);
  scn_corr_reduce<<<dim3(16, 8), 256, 0, stream>>>(part, invn, At);
  scn_wcast<<<dim3((1024 * KPAD) / 256), 256, 0, stream>>>(conv_w, Wb);
  scn_gemm<<<dim3(8, 4, 8), 512, 131072, stream>>>(Wb, At, conv_b, out);
}